// Round 7
// baseline (213.002 us; speedup 1.0000x reference)
//
#include <hip/hip_runtime.h>
#include <hip/hip_bf16.h>

#define BS 512
#define LL 128
#define DD 512
#define KK 30
#define GG 8
#define EE 2048
#define HH 1024
#define NROWS (BS*KK)   // 15360
#define NG (BS/GG)      // 64

typedef __attribute__((ext_vector_type(8))) short bf16x8;
typedef __attribute__((ext_vector_type(4))) float f32x4;
typedef __attribute__((address_space(1))) const unsigned int gu32;
typedef __attribute__((address_space(3))) unsigned int lu32;

__device__ __forceinline__ unsigned short f2bf(float f){
  unsigned int x = __float_as_uint(f);
  x = (x + 0x7FFFu + ((x >> 16) & 1u)) >> 16;   // round-to-nearest-even
  return (unsigned short)x;
}
__device__ __forceinline__ float bf2f(unsigned short u){
  return __uint_as_float(((unsigned int)u) << 16);
}
__device__ __forceinline__ unsigned fkey(float f){   // monotonic float->uint
  unsigned b = __float_as_uint(f);
  return (b & 0x80000000u) ? ~b : (b | 0x80000000u);
}
__device__ __forceinline__ float fdec(unsigned k){
  unsigned b = (k & 0x80000000u) ? (k & 0x7FFFFFFFu) : ~k;
  return __uint_as_float(b);
}

// ---------------------------------------------------------------------------
// Kernel 1: per-batch eos/argmax, lengths, masked row, top-30 — single wave,
// shuffle-only. Tie rule: larger value, smaller index.
// ---------------------------------------------------------------------------
__global__ __launch_bounds__(64) void k_prep(const float* __restrict__ atten,
                                             const int* __restrict__ text,
                                             int* __restrict__ idx,
                                             int* __restrict__ lensk){
  const int b = blockIdx.x;
  const int lane = threadIdx.x;
  const int t0 = text[b*LL + lane];
  const int t1 = text[b*LL + 64 + lane];

  int v, vi;
  if(t1 > t0){ v = t1; vi = lane + 64; } else { v = t0; vi = lane; }
#pragma unroll
  for(int off = 32; off; off >>= 1){
    const int ov = __shfl_xor(v, off), oi = __shfl_xor(vi, off);
    if(ov > v || (ov == v && oi < vi)){ v = ov; vi = oi; }
  }
  const int eos = vi;

  const unsigned long long mb0 = __ballot(t0 != 0), mb1 = __ballot(t1 != 0);
  if(lane == 0) lensk[b] = min(__popcll(mb0) + __popcll(mb1) - 2, KK);

  const float a0 = atten[(size_t)b*LL*LL + (size_t)eos*LL + lane];
  const float a1 = atten[(size_t)b*LL*LL + (size_t)eos*LL + 64 + lane];
  float r0 = (t0 == 0) ? 0.f : ((lane == 0 || lane == eos) ? -1.f : a0);
  float r1 = (t1 == 0) ? 0.f : ((lane + 64 == eos) ? -1.f : a1);

  for(int k = 0; k < KK; k++){
    float mv; int mi;
    if(r1 > r0){ mv = r1; mi = lane + 64; } else { mv = r0; mi = lane; }
#pragma unroll
    for(int off = 32; off; off >>= 1){
      const float ov = __shfl_xor(mv, off); const int oi = __shfl_xor(mi, off);
      if(ov > mv || (ov == mv && oi < mi)){ mv = ov; mi = oi; }
    }
    if(lane == 0) idx[b*KK + k] = mi;
    if(mi == lane)      r0 = -3.f;
    if(mi == lane + 64) r1 = -3.f;
  }
}

// ---------------------------------------------------------------------------
// Kernel 2: gather + l2norm (bf16 out) + 8 expert dot products.
// ---------------------------------------------------------------------------
__global__ __launch_bounds__(128) void k_gather(const float* __restrict__ features,
                                                const float* __restrict__ dlp_w,
                                                const float* __restrict__ dlp_b,
                                                const int* __restrict__ idx,
                                                unsigned short* __restrict__ nfeats,
                                                float* __restrict__ hval){
  const int r = blockIdx.x;
  const int b = r / KK;
  const int t = threadIdx.x;
  const int l = idx[r];

  const float4 v = ((const float4*)features)[((size_t)b*LL + l)*(DD/4) + t];
  float ss = v.x*v.x + v.y*v.y + v.z*v.z + v.w*v.w;
  float hg[GG];
#pragma unroll
  for(int g = 0; g < GG; g++){
    const float4 w = ((const float4*)dlp_w)[g*(DD/4) + t];
    hg[g] = v.x*w.x + v.y*w.y + v.z*w.z + v.w*w.w;
  }
#pragma unroll
  for(int off = 32; off > 0; off >>= 1){
    ss += __shfl_down(ss, off);
#pragma unroll
    for(int g = 0; g < GG; g++) hg[g] += __shfl_down(hg[g], off);
  }
  __shared__ float red[2][9];
  __shared__ float s_rn;
  const int wave = t >> 6, lane = t & 63;
  if(lane == 0){
    red[wave][0] = ss;
#pragma unroll
    for(int g = 0; g < GG; g++) red[wave][1+g] = hg[g];
  }
  __syncthreads();
  if(t == 0) s_rn = 1.0f / (sqrtf(red[0][0] + red[1][0]) + 1e-8f);
  if(t < GG) hval[(size_t)r*GG + t] = red[0][1+t] + red[1][1+t] + dlp_b[t];
  __syncthreads();
  const float rn = s_rn;
  ushort4 u;
  u.x = f2bf(v.x*rn); u.y = f2bf(v.y*rn); u.z = f2bf(v.z*rn); u.w = f2bf(v.w*rn);
  ((ushort4*)nfeats)[(size_t)r*(DD/4) + t] = u;
}

// ---------------------------------------------------------------------------
// Kernel 3: grouped-expert linear -> nbbf (bf16).
// ---------------------------------------------------------------------------
__global__ __launch_bounds__(256) void k_dlp(const float* __restrict__ hval,
                                             const float* __restrict__ dlp_lw,
                                             const float* __restrict__ dlp_lb,
                                             unsigned short* __restrict__ nbbf){
  const int et = blockIdx.x;
  const int n  = blockIdx.y;
  const int tid = threadIdx.x;
  __shared__ float hs[GG][GG*KK];
  for(int i = tid; i < GG*GG*KK; i += 256){
    const int g = i / (GG*KK), tt = i % (GG*KK);
    const int m = tt / KK, kq = tt % KK;
    hs[g][tt] = hval[(size_t)(((n*GG + m)*KK) + kq)*GG + g];
  }
  __syncthreads();
  const int h = tid >> 7, c = tid & 127;
  const int e = et*128 + c;
  float acc[4] = {0.f, 0.f, 0.f, 0.f};
#pragma unroll 4
  for(int k = 0; k < GG*KK; k++){
    const float w = dlp_lw[(size_t)k*EE + e];
#pragma unroll
    for(int rr = 0; rr < 4; rr++) acc[rr] += hs[h*4 + rr][k] * w;
  }
  const float lb = dlp_lb[e];
#pragma unroll
  for(int rr = 0; rr < 4; rr++)
    nbbf[(size_t)(n*GG + h*4 + rr)*EE + e] = f2bf(acc[rr] + lb);
}

// ---------------------------------------------------------------------------
// Kernel 4: l2-normalize nbbf rows in place (bf16).
// ---------------------------------------------------------------------------
__global__ __launch_bounds__(256) void k_l2nb(unsigned short* __restrict__ nbbf){
  const int b = blockIdx.x, t = threadIdx.x;
  uint4* p = (uint4*)(nbbf + (size_t)b*EE);
  uint4 u = p[t];
  unsigned short* us = (unsigned short*)&u;
  float f[8]; float ss = 0.f;
#pragma unroll
  for(int j = 0; j < 8; j++){ f[j] = bf2f(us[j]); ss += f[j]*f[j]; }
#pragma unroll
  for(int off = 32; off > 0; off >>= 1) ss += __shfl_down(ss, off);
  __shared__ float red[4];
  __shared__ float s_rn;
  if((t & 63) == 0) red[t >> 6] = ss;
  __syncthreads();
  if(t == 0) s_rn = 1.0f / (sqrtf(red[0] + red[1] + red[2] + red[3]) + 1e-8f);
  __syncthreads();
  const float rn = s_rn;
#pragma unroll
  for(int j = 0; j < 8; j++) us[j] = f2bf(f[j]*rn);
  p[t] = u;
}

// ---------------------------------------------------------------------------
// Kernel 5: weight transpose+convert: src[K][N] f32 -> dst[N][K] bf16.
// ---------------------------------------------------------------------------
__global__ __launch_bounds__(256) void k_wcvt(const float* __restrict__ src,
                                              unsigned short* __restrict__ dst,
                                              int Kd, int Nd){
  __shared__ float tile[32][33];
  const int n0 = blockIdx.x*32, k0 = blockIdx.y*32;
  const int r = threadIdx.x >> 3, c4 = (threadIdx.x & 7)*4;
  const float4 v = *(const float4*)(src + (size_t)(k0 + r)*Nd + n0 + c4);
  tile[r][c4+0] = v.x; tile[r][c4+1] = v.y; tile[r][c4+2] = v.z; tile[r][c4+3] = v.w;
  __syncthreads();
  ushort4 u;
  u.x = f2bf(tile[c4+0][r]); u.y = f2bf(tile[c4+1][r]);
  u.z = f2bf(tile[c4+2][r]); u.w = f2bf(tile[c4+3][r]);
  *(ushort4*)(dst + (size_t)(n0 + r)*Kd + k0 + c4) = u;
}

// ---------------------------------------------------------------------------
// Kernel 6: MFMA bf16 GEMM, 256x256 tile, BK=64, 8 waves (2Mx4N), double-
// buffered 128KiB LDS. 8-phase m201-style schedule: each K-tile = 4 phases
// of 16 MFMA; per phase {pre-barrier ds_reads + 2 stage-gloads -> [vmcnt] ->
// s_barrier -> lgkmcnt(0)+sched_barrier -> setprio(1) MFMA setprio(0) ->
// s_barrier}. Stage order per tile: A0,A2,B0..B3,A1,A3 (need-first);
// vmcnt(2) only at ph1/ph4 (in-order retirement => exactly the needed chunks
// certified), never vmcnt(0) in the main loop. Row-XOR granule swizzle
// (0 bank conflicts measured). Last tile peeled (drain with vmcnt(0)).
// ---------------------------------------------------------------------------
template<int KD, int ND, bool POOL, bool STATS, int NBX>
__global__ __launch_bounds__(512, 2) void k_mgemm(const unsigned short* __restrict__ A,
                                                  const unsigned short* __restrict__ Bt,
                                                  const float* __restrict__ bias,
                                                  unsigned short* __restrict__ obf,
                                                  const int* __restrict__ lensk,
                                                  unsigned* __restrict__ pkey,
                                                  float* __restrict__ psum,
                                                  float* __restrict__ psq){
  __shared__ short S[2][2][256*64];   // [buf][A|B][row*64+col] = 128 KiB
  const int tid  = threadIdx.x;
  const int wave = tid >> 6, lane = tid & 63;
  const int wr = wave >> 2, wc = wave & 3;        // 2M x 4N waves
  const int lrow = lane & 15, kg = lane >> 4;

  const int nwg = gridDim.x, cpx = nwg >> 3;      // grid % 8 == 0
  const int bid = (blockIdx.x & 7)*cpx + (blockIdx.x >> 3);
  const int bx = bid % NBX, by = bid / NBX;
  const int m0 = by*256, n0 = bx*256;

  const unsigned short* Ab = A  + (size_t)m0*KD;
  const unsigned short* Bb = Bt + (size_t)n0*KD;

  // one chunk = 64 rows x 64 k, 1 gload_lds x 16B per thread
#define STG_A(tt, p, c) { \
  const int i_ = tid + (c)*512; const int r_ = i_ >> 3; \
  const int g_ = (i_ & 7) ^ (r_ & 7); \
  __builtin_amdgcn_global_load_lds((gu32*)(Ab + (size_t)r_*KD + (tt)*64 + g_*8), \
                                   (lu32*)(&S[p][0][i_*8]), 16, 0, 0); }
#define STG_B(tt, p, c) { \
  const int i_ = tid + (c)*512; const int r_ = i_ >> 3; \
  const int g_ = (i_ & 7) ^ (r_ & 7); \
  __builtin_amdgcn_global_load_lds((gu32*)(Bb + (size_t)r_*KD + (tt)*64 + g_*8), \
                                   (lu32*)(&S[p][1][i_*8]), 16, 0, 0); }

#define DSR_B(gx)  _Pragma("unroll") for(int n = 0; n < 4; n++) \
    bg[n] = *(const bf16x8*)(Bbuf + (brow + n*16)*64 + (gx));
#define DSR_AL(gx) _Pragma("unroll") for(int m = 0; m < 4; m++) \
    af[m] = *(const bf16x8*)(Abuf + (arow + m*16)*64 + (gx));
#define DSR_AH(gx) _Pragma("unroll") for(int m = 0; m < 4; m++) \
    af[m] = *(const bf16x8*)(Abuf + (arow + 64 + m*16)*64 + (gx));
#define FENCE asm volatile("" ::: "memory")
#define BARR  do{ FENCE; __builtin_amdgcn_s_barrier(); FENCE; }while(0)
#define LGK0  do{ asm volatile("s_waitcnt lgkmcnt(0)" ::: "memory"); \
                  __builtin_amdgcn_sched_barrier(0); }while(0)
#define VMW(n) asm volatile("s_waitcnt vmcnt(" #n ")" ::: "memory")
#define MFMA_L do{ __builtin_amdgcn_s_setprio(1); \
  _Pragma("unroll") for(int m = 0; m < 4; m++) \
  _Pragma("unroll") for(int n = 0; n < 4; n++) \
    acc[m][n] = __builtin_amdgcn_mfma_f32_16x16x32_bf16(af[m], bg[n], acc[m][n], 0, 0, 0); \
  __builtin_amdgcn_s_setprio(0); }while(0)
#define MFMA_H do{ __builtin_amdgcn_s_setprio(1); \
  _Pragma("unroll") for(int m = 0; m < 4; m++) \
  _Pragma("unroll") for(int n = 0; n < 4; n++) \
    acc[4+m][n] = __builtin_amdgcn_mfma_f32_16x16x32_bf16(af[m], bg[n], acc[4+m][n], 0, 0, 0); \
  __builtin_amdgcn_s_setprio(0); }while(0)

  f32x4 acc[8][4] = {};
  const int NT = KD/64;

  const int arow = wr*128 + lrow;     // + m*16
  const int brow = wc*64  + lrow;     // + n*16  (16|stride => row&7 == lrow&7)
  const int gx0 = (kg       ^ (lrow & 7))*8;     // swizzled granule, kk=0
  const int gx1 = ((4 + kg) ^ (lrow & 7))*8;     // swizzled granule, kk=1

  // prologue: tile 0 in need-first order
  STG_A(0, 0, 0) STG_A(0, 0, 2)
  STG_B(0, 0, 0) STG_B(0, 0, 1) STG_B(0, 0, 2) STG_B(0, 0, 3)
  STG_A(0, 0, 1) STG_A(0, 0, 3)
  VMW(2); BARR;                       // first 6 chunks of tile 0 in LDS

#pragma unroll 1
  for(int t = 0; t < NT-1; t++){
    const int p = t & 1, q = p ^ 1;
    const short* Abuf = &S[p][0][0];
    const short* Bbuf = &S[p][1][0];
    bf16x8 bg[4], af[4];
    // ---- ph1: kk0, m-low ----
    DSR_B(gx0); DSR_AL(gx0);
    STG_A(t+1, q, 0) STG_A(t+1, q, 2)
    VMW(2);                           // tile t's A1,A3 landed (for ph2)
    BARR; LGK0;
    MFMA_L;
    BARR;
    // ---- ph2: kk0, m-high ----
    DSR_AH(gx0);
    STG_B(t+1, q, 0) STG_B(t+1, q, 1)
    BARR; LGK0;
    MFMA_H;
    BARR;
    // ---- ph3: kk1, m-low ----
    DSR_B(gx1); DSR_AL(gx1);
    STG_B(t+1, q, 2) STG_B(t+1, q, 3)
    BARR; LGK0;
    MFMA_L;
    BARR;
    // ---- ph4: kk1, m-high ----
    DSR_AH(gx1);
    STG_A(t+1, q, 1) STG_A(t+1, q, 3)
    VMW(2);                           // tile t+1's first 6 landed (for next ph1)
    BARR; LGK0;
    MFMA_H;
    BARR;
  }
  { // epilogue: tile NT-1, no staging
    const int p = (NT-1) & 1;
    const short* Abuf = &S[p][0][0];
    const short* Bbuf = &S[p][1][0];
    bf16x8 bg[4], af[4];
    DSR_B(gx0); DSR_AL(gx0);
    VMW(0);                           // drain A1,A3 (for ph2)
    BARR; LGK0;
    MFMA_L;
    BARR;
    DSR_AH(gx0);
    BARR; LGK0;
    MFMA_H;
    BARR;
    DSR_B(gx1); DSR_AL(gx1);
    BARR; LGK0;
    MFMA_L;
    BARR;
    DSR_AH(gx1);
    LGK0;
    MFMA_H;
  }
#undef STG_A
#undef STG_B
#undef DSR_B
#undef DSR_AL
#undef DSR_AH
#undef MFMA_L
#undef MFMA_H

  if constexpr (!POOL){
    const int colb = n0 + wc*64 + lrow;
#pragma unroll
    for(int n = 0; n < 4; n++){
      const float bb = bias[colb + n*16];
      if constexpr (STATS){
        float sv = 0.f, qv = 0.f;
#pragma unroll
        for(int m = 0; m < 8; m++)
#pragma unroll
          for(int r = 0; r < 4; r++){
            const float v = acc[m][n][r] + bb; sv += v; qv += v*v;
          }
        sv += __shfl_xor(sv, 16); sv += __shfl_xor(sv, 32);
        qv += __shfl_xor(qv, 16); qv += __shfl_xor(qv, 32);
        if(lane < 16){
          psum[(size_t)(by*2 + wr)*ND + colb + n*16] = sv;
          psq [(size_t)(by*2 + wr)*ND + colb + n*16] = qv;
        }
      }
#pragma unroll
      for(int m = 0; m < 8; m++){
        const int row = m0 + wr*128 + m*16 + kg*4;
#pragma unroll
        for(int r = 0; r < 4; r++)
          obf[(size_t)(row + r)*ND + colb + n*16] = f2bf(acc[m][n][r] + bb);
      }
    }
  } else {
    // ---- two-level segmented max-pool: regs -> LDS (atomicMax) -> global ---
    __syncthreads();                               // all waves' S reads retired
    unsigned* pool = (unsigned*)&S[0][0][0];       // [nseg][256] fkeys, <=10KB
    const int b0 = m0 / KK;
    const int b1 = (m0 + 255) / KK;
    const int nseg = b1 - b0 + 1;                  // <= 10
    for(int i = tid; i < nseg*256; i += 512) pool[i] = 0x007FFFFFu;  // fkey(-inf)
    __syncthreads();
    const int lcol = wc*64 + lrow;                 // + n*16
    {
      int cur_b = -1;
      float mx[4];
#pragma unroll
      for(int m = 0; m < 8; m++){
#pragma unroll
        for(int r = 0; r < 4; r++){
          const int row = m0 + wr*128 + m*16 + kg*4 + r;
          const int bt = row / KK;
          const int rr = row - bt*KK;
          if(bt != cur_b){
            if(cur_b >= 0){
#pragma unroll
              for(int n = 0; n < 4; n++)
                atomicMax(&pool[(cur_b - b0)*256 + lcol + n*16], fkey(mx[n]));
            }
            cur_b = bt;
#pragma unroll
            for(int n = 0; n < 4; n++) mx[n] = -INFINITY;
          }
          if(rr < lensk[bt]){
#pragma unroll
            for(int n = 0; n < 4; n++) mx[n] = fmaxf(mx[n], acc[m][n][r]);
          }
        }
      }
#pragma unroll
      for(int n = 0; n < 4; n++)
        atomicMax(&pool[(cur_b - b0)*256 + lcol + n*16], fkey(mx[n]));
    }
    __syncthreads();
    for(int e = tid; e < nseg*256; e += 512){
      const int seg = e >> 8, col = e & 255;
      atomicMax(&pkey[(size_t)(b0 + seg)*ND + n0 + col], pool[e]);
    }
  }
}

// ---------------------------------------------------------------------------
// Kernel 7: BN finalize from GEMM1's fused partials (120 row-groups).
// ---------------------------------------------------------------------------
__global__ __launch_bounds__(256) void k_bnfin(const float* __restrict__ psum,
                                               const float* __restrict__ psq,
                                               const float* __restrict__ bn_g,
                                               const float* __restrict__ bn_b,
                                               float* __restrict__ sc,
                                               float* __restrict__ sh){
  const int c = blockIdx.x*256 + threadIdx.x;
  float s = 0.f, q = 0.f;
  for(int i = 0; i < 120; i++){ s += psum[(size_t)i*HH + c]; q += psq[(size_t)i*HH + c]; }
  const float mu  = s * (1.0f/NROWS);
  const float var = q * (1.0f/NROWS) - mu*mu;
  const float sv  = bn_g[c] / sqrtf(var + 1e-5f);
  sc[c] = sv;
  sh[c] = bn_b[c] - mu*sv;
}

// ---------------------------------------------------------------------------
// Kernel 8: BN+ReLU in place on x1 (bf16) + pkey init (overlay region
// psum/psq/w1t/hval/idx is dead by now; lensk lies outside the overlay).
// ---------------------------------------------------------------------------
__global__ __launch_bounds__(256) void k_bnrelu(unsigned short* __restrict__ x1,
                                                const float* __restrict__ sc,
                                                const float* __restrict__ sh,
                                                unsigned* __restrict__ pkey){
  const size_t i = (size_t)blockIdx.x*256 + threadIdx.x;   // chunk of 8 bf16
  const int c0 = (int)((i*8) & (HH-1));
  uint4 u = ((uint4*)x1)[i];
  unsigned short* us = (unsigned short*)&u;
  const float4 s0 = *(const float4*)(sc + c0), s1 = *(const float4*)(sc + c0 + 4);
  const float4 h0 = *(const float4*)(sh + c0), h1 = *(const float4*)(sh + c0 + 4);
  const float scv[8] = {s0.x,s0.y,s0.z,s0.w,s1.x,s1.y,s1.z,s1.w};
  const float shv[8] = {h0.x,h0.y,h0.z,h0.w,h1.x,h1.y,h1.z,h1.w};
#pragma unroll
  for(int j = 0; j < 8; j++)
    us[j] = f2bf(fmaxf(bf2f(us[j])*scv[j] + shv[j], 0.f));
  ((uint4*)x1)[i] = u;
  if(blockIdx.x < 1024)
    ((uint4*)pkey)[blockIdx.x*256 + threadIdx.x] =
        make_uint4(0x007FFFFFu, 0x007FFFFFu, 0x007FFFFFu, 0x007FFFFFu);  // key(-inf)
}

// ---------------------------------------------------------------------------
// Kernel 9: finalize output.
// ---------------------------------------------------------------------------
__global__ __launch_bounds__(256) void k_final(const unsigned* __restrict__ pkey,
                                               const float* __restrict__ b2,
                                               const unsigned short* __restrict__ nbbf,
                                               float* __restrict__ out){
  const size_t i = (size_t)blockIdx.x*256 + threadIdx.x;   // per 4 elems
  const int c0 = (int)((i*4) & (EE-1));
  const uint4 k = ((const uint4*)pkey)[i];
  const ushort4 nb4 = ((const ushort4*)nbbf)[i];
  const float4 b = *(const float4*)(b2 + c0);
  float4 o;
  o.x = fdec(k.x) + b.x + bf2f(nb4.x);
  o.y = fdec(k.y) + b.y + bf2f(nb4.y);
  o.z = fdec(k.z) + b.z + bf2f(nb4.z);
  o.w = fdec(k.w) + b.w + bf2f(nb4.w);
  ((float4*)out)[i] = o;
}

// ---------------------------------------------------------------------------
extern "C" void kernel_launch(void* const* d_in, const int* in_sizes, int n_in,
                              void* d_out, int out_size, void* d_ws, size_t ws_size,
                              hipStream_t stream){
  const float* features = (const float*)d_in[0];
  const float* atten    = (const float*)d_in[1];
  const int*   text     = (const int*)  d_in[2];
  const float* dlp_w    = (const float*)d_in[4];
  const float* dlp_b    = (const float*)d_in[5];
  const float* dlp_lw   = (const float*)d_in[6];
  const float* dlp_lb   = (const float*)d_in[7];
  const float* w1       = (const float*)d_in[8];
  const float* b1       = (const float*)d_in[9];
  const float* bn_g     = (const float*)d_in[10];
  const float* bn_b     = (const float*)d_in[11];
  const float* w2       = (const float*)d_in[12];
  const float* b2       = (const float*)d_in[13];
  float* out = (float*)d_out;

  // Workspace layout with lifetime aliasing:
  char* ws = (char*)d_ws;
  float*          psum   = (float*)(ws + 0);               //   491,520 (120x1024)
  float*          psq    = (float*)(ws + 983040);          //   491,520
  unsigned short* w1t    = (unsigned short*)(ws + 1966080);// 1,048,576
  float*          hval   = (float*)(ws + 3014656);         //   491,520
  int*            idx    = (int*)(ws + 3506176);           //    61,440
  unsigned*       pkey   = (unsigned*)(ws + 0);            // 4,194,304 (overlay, live from k_bnrelu on)
  int*            lensk  = (int*)(ws + 4194304);           //     2,048
  float*          sc     = (float*)(ws + 4196352);         //     4,096
  float*          sh     = (float*)(ws + 4200448);         //     4,096
  unsigned short* nfeats = (unsigned short*)(ws + 4204544);// 15,728,640
  unsigned short* w2t    = (unsigned short*)(ws + 4204544);// 4,194,304 (overlays nfeats after gemm1)
  unsigned short* x1     = (unsigned short*)(ws + 19933184);//31,457,280
  unsigned short* nbbf   = (unsigned short*)(ws + 51390464);// 2,097,152

  k_wcvt<<<dim3(HH/32, DD/32), 256, 0, stream>>>(w1, w1t, DD, HH);
  k_prep<<<BS, 64, 0, stream>>>(atten, text, idx, lensk);
  k_gather<<<NROWS, 128, 0, stream>>>(features, dlp_w, dlp_b, idx, nfeats, hval);
  k_dlp<<<dim3(16, NG), 256, 0, stream>>>(hval, dlp_lw, dlp_lb, nbbf);
  k_l2nb<<<BS, 256, 0, stream>>>(nbbf);
  k_mgemm<DD, HH, false, true, HH/256><<<(HH/256)*(NROWS/256), 512, 0, stream>>>(
      nfeats, w1t, b1, x1, nullptr, nullptr, psum, psq);
  k_wcvt<<<dim3(EE/32, HH/32), 256, 0, stream>>>(w2, w2t, HH, EE);   // nfeats dead now
  k_bnfin<<<4, 256, 0, stream>>>(psum, psq, bn_g, bn_b, sc, sh);
  k_bnrelu<<<(NROWS*HH/8)/256, 256, 0, stream>>>(x1, sc, sh, pkey);
  k_mgemm<HH, EE, true, false, EE/256><<<(EE/256)*(NROWS/256), 512, 0, stream>>>(
      x1, w2t, nullptr, nullptr, lensk, pkey, nullptr, nullptr);
  k_final<<<(BS*EE/4)/256, 256, 0, stream>>>(pkey, b2, nbbf, out);
}

// Round 9
// 182.950 us; speedup vs baseline: 1.1643x; 1.1643x over previous
//
#include <hip/hip_runtime.h>
#include <hip/hip_bf16.h>

#define BS 512
#define LL 128
#define DD 512
#define KK 30
#define GG 8
#define EE 2048
#define HH 1024
#define NROWS (BS*KK)   // 15360
#define NG (BS/GG)      // 64

typedef __attribute__((ext_vector_type(8))) short bf16x8;
typedef __attribute__((ext_vector_type(4))) float f32x4;
typedef __attribute__((address_space(1))) const unsigned int gu32;
typedef __attribute__((address_space(3))) unsigned int lu32;

__device__ __forceinline__ unsigned short f2bf(float f){
  unsigned int x = __float_as_uint(f);
  x = (x + 0x7FFFu + ((x >> 16) & 1u)) >> 16;   // round-to-nearest-even
  return (unsigned short)x;
}
__device__ __forceinline__ float bf2f(unsigned short u){
  return __uint_as_float(((unsigned int)u) << 16);
}
__device__ __forceinline__ unsigned fkey(float f){   // monotonic float->uint
  unsigned b = __float_as_uint(f);
  return (b & 0x80000000u) ? ~b : (b | 0x80000000u);
}
__device__ __forceinline__ float fdec(unsigned k){
  unsigned b = (k & 0x80000000u) ? (k & 0x7FFFFFFFu) : ~k;
  return __uint_as_float(b);
}

#define FENCE asm volatile("" ::: "memory")
#define BARR  do{ FENCE; __builtin_amdgcn_s_barrier(); FENCE; }while(0)
#define LGK0  do{ asm volatile("s_waitcnt lgkmcnt(0)" ::: "memory"); \
                  __builtin_amdgcn_sched_barrier(0); }while(0)
#define VMW(n) asm volatile("s_waitcnt vmcnt(" #n ")" ::: "memory")

// ---------------------------------------------------------------------------
// Kernel 1 (fused): blocks [0,512): per-batch prep (wave0: eos/lengths/top-30,
// shuffle-only) + gather of 30 rows (one row per wave per iter, shuffle-only
// reductions) producing nfeats (l2-normed bf16) and hval (8 expert dots).
// Blocks [512,1024): w1[512,1024] f32 -> w1t[1024,512] bf16 transpose.
// ---------------------------------------------------------------------------
__global__ __launch_bounds__(256) void k_pg(const float* __restrict__ atten,
                                            const int* __restrict__ text,
                                            const float* __restrict__ features,
                                            const float* __restrict__ dlp_w,
                                            const float* __restrict__ dlp_b,
                                            const float* __restrict__ w1,
                                            unsigned short* __restrict__ w1t,
                                            unsigned short* __restrict__ nfeats,
                                            float* __restrict__ hval,
                                            int* __restrict__ lensk){
  __shared__ int sidx[KK];
  __shared__ float tile[32][33];

  if(blockIdx.x >= BS){   // ---- w1 transpose+convert half ----
    const int blk = blockIdx.x - BS;          // 512 blocks: 32 n-tiles x 16 k-tiles
    const int n0 = (blk & 31)*32, k0 = (blk >> 5)*32;
    const int r = threadIdx.x >> 3, c4 = (threadIdx.x & 7)*4;
    const float4 v = *(const float4*)(w1 + (size_t)(k0 + r)*HH + n0 + c4);
    tile[r][c4+0] = v.x; tile[r][c4+1] = v.y; tile[r][c4+2] = v.z; tile[r][c4+3] = v.w;
    __syncthreads();
    ushort4 u;
    u.x = f2bf(tile[c4+0][r]); u.y = f2bf(tile[c4+1][r]);
    u.z = f2bf(tile[c4+2][r]); u.w = f2bf(tile[c4+3][r]);
    *(ushort4*)(w1t + (size_t)(n0 + r)*DD + k0 + c4) = u;
    return;
  }

  const int b = blockIdx.x;
  const int tid = threadIdx.x;
  const int wv = tid >> 6, lane = tid & 63;

  if(wv == 0){   // ---- prep on wave 0 (shuffle-only) ----
    const int t0 = text[b*LL + lane];
    const int t1 = text[b*LL + 64 + lane];
    int v, vi;
    if(t1 > t0){ v = t1; vi = lane + 64; } else { v = t0; vi = lane; }
#pragma unroll
    for(int off = 32; off; off >>= 1){
      const int ov = __shfl_xor(v, off), oi = __shfl_xor(vi, off);
      if(ov > v || (ov == v && oi < vi)){ v = ov; vi = oi; }
    }
    const int eos = vi;
    const unsigned long long mb0 = __ballot(t0 != 0), mb1 = __ballot(t1 != 0);
    if(lane == 0) lensk[b] = min(__popcll(mb0) + __popcll(mb1) - 2, KK);

    const float a0 = atten[(size_t)b*LL*LL + (size_t)eos*LL + lane];
    const float a1 = atten[(size_t)b*LL*LL + (size_t)eos*LL + 64 + lane];
    float r0 = (t0 == 0) ? 0.f : ((lane == 0 || lane == eos) ? -1.f : a0);
    float r1 = (t1 == 0) ? 0.f : ((lane + 64 == eos) ? -1.f : a1);
    for(int k = 0; k < KK; k++){
      float mv; int mi;
      if(r1 > r0){ mv = r1; mi = lane + 64; } else { mv = r0; mi = lane; }
#pragma unroll
      for(int off = 32; off; off >>= 1){
        const float ov = __shfl_xor(mv, off); const int oi = __shfl_xor(mi, off);
        if(ov > mv || (ov == mv && oi < mi)){ mv = ov; mi = oi; }
      }
      if(lane == 0) sidx[k] = mi;
      if(mi == lane)      r0 = -3.f;
      if(mi == lane + 64) r1 = -3.f;
    }
  }
  __syncthreads();

  // ---- gather: one row per wave per iteration, 8 iterations ----
  for(int it = 0; it < 8; it++){
    const int r = it*4 + wv;
    if(r >= KK) break;
    const int l = sidx[r];
    const float4* fp = (const float4*)features + ((size_t)b*LL + l)*(DD/4);
    const float4 v0 = fp[lane], v1 = fp[64 + lane];
    float ss = v0.x*v0.x + v0.y*v0.y + v0.z*v0.z + v0.w*v0.w
             + v1.x*v1.x + v1.y*v1.y + v1.z*v1.z + v1.w*v1.w;
#pragma unroll
    for(int off = 32; off; off >>= 1) ss += __shfl_xor(ss, off);
    float hout = 0.f;
#pragma unroll
    for(int g = 0; g < GG; g++){
      const float4 w0 = ((const float4*)dlp_w)[g*(DD/4) + lane];
      const float4 w1v = ((const float4*)dlp_w)[g*(DD/4) + 64 + lane];
      float hg = v0.x*w0.x + v0.y*w0.y + v0.z*w0.z + v0.w*w0.w
               + v1.x*w1v.x + v1.y*w1v.y + v1.z*w1v.z + v1.w*w1v.w;
#pragma unroll
      for(int off = 32; off; off >>= 1) hg += __shfl_xor(hg, off);
      if(lane == g) hout = hg;
    }
    if(lane < GG) hval[(size_t)(b*KK + r)*GG + lane] = hout + dlp_b[lane];
    const float rn = 1.0f / (sqrtf(ss) + 1e-8f);
    ushort4 u0, u1;
    u0.x = f2bf(v0.x*rn); u0.y = f2bf(v0.y*rn); u0.z = f2bf(v0.z*rn); u0.w = f2bf(v0.w*rn);
    u1.x = f2bf(v1.x*rn); u1.y = f2bf(v1.y*rn); u1.z = f2bf(v1.z*rn); u1.w = f2bf(v1.w*rn);
    ushort4* np = (ushort4*)nfeats + (size_t)(b*KK + r)*(DD/4);   // FIX: 128 ushort4/row
    np[lane] = u0; np[64 + lane] = u1;
  }
}

// ---------------------------------------------------------------------------
// Kernel 2: grouped-expert linear -> nbbf (bf16).
// ---------------------------------------------------------------------------
__global__ __launch_bounds__(256) void k_dlp(const float* __restrict__ hval,
                                             const float* __restrict__ dlp_lw,
                                             const float* __restrict__ dlp_lb,
                                             unsigned short* __restrict__ nbbf){
  const int et = blockIdx.x;
  const int n  = blockIdx.y;
  const int tid = threadIdx.x;
  __shared__ float hs[GG][GG*KK];
  for(int i = tid; i < GG*GG*KK; i += 256){
    const int g = i / (GG*KK), tt = i % (GG*KK);
    const int m = tt / KK, kq = tt % KK;
    hs[g][tt] = hval[(size_t)(((n*GG + m)*KK) + kq)*GG + g];
  }
  __syncthreads();
  const int h = tid >> 7, c = tid & 127;
  const int e = et*128 + c;
  float acc[4] = {0.f, 0.f, 0.f, 0.f};
#pragma unroll 4
  for(int k = 0; k < GG*KK; k++){
    const float w = dlp_lw[(size_t)k*EE + e];
#pragma unroll
    for(int rr = 0; rr < 4; rr++) acc[rr] += hs[h*4 + rr][k] * w;
  }
  const float lb = dlp_lb[e];
#pragma unroll
  for(int rr = 0; rr < 4; rr++)
    nbbf[(size_t)(n*GG + h*4 + rr)*EE + e] = f2bf(acc[rr] + lb);
}

// ---------------------------------------------------------------------------
// Kernel 3: l2-normalize nbbf rows in place (bf16).
// ---------------------------------------------------------------------------
__global__ __launch_bounds__(256) void k_l2nb(unsigned short* __restrict__ nbbf){
  const int b = blockIdx.x, t = threadIdx.x;
  uint4* p = (uint4*)(nbbf + (size_t)b*EE);
  uint4 u = p[t];
  unsigned short* us = (unsigned short*)&u;
  float f[8]; float ss = 0.f;
#pragma unroll
  for(int j = 0; j < 8; j++){ f[j] = bf2f(us[j]); ss += f[j]*f[j]; }
#pragma unroll
  for(int off = 32; off > 0; off >>= 1) ss += __shfl_down(ss, off);
  __shared__ float red[4];
  __shared__ float s_rn;
  if((t & 63) == 0) red[t >> 6] = ss;
  __syncthreads();
  if(t == 0) s_rn = 1.0f / (sqrtf(red[0] + red[1] + red[2] + red[3]) + 1e-8f);
  __syncthreads();
  const float rn = s_rn;
#pragma unroll
  for(int j = 0; j < 8; j++) us[j] = f2bf(f[j]*rn);
  p[t] = u;
}

// ---------------------------------------------------------------------------
// Kernel 4 (GEMM1): x1 = nfeats[15360,512] @ w1t^T + b1, bf16 out, fused BN
// stats. 128x128 tile, BK=64, 4 waves (2Mx2N), 64KiB double-buffered LDS ->
// 2 blocks/CU (grid 960 = all CUs busy, cross-block overlap hides barrier
// drains). 2-tile-lead counted vmcnt(8). Row-XOR granule swizzle.
// ---------------------------------------------------------------------------
__global__ __launch_bounds__(256, 2) void k_g1(const unsigned short* __restrict__ A,
                                               const unsigned short* __restrict__ Bt,
                                               const float* __restrict__ bias,
                                               unsigned short* __restrict__ obf,
                                               float* __restrict__ psum,
                                               float* __restrict__ psq){
  const int KD = DD, ND = HH, NBX = HH/128;      // 512, 1024, 8
  __shared__ short S[2][2][128*64];              // 64 KiB
  const int tid  = threadIdx.x;
  const int wave = tid >> 6, lane = tid & 63;
  const int wr = wave >> 1, wc = wave & 1;       // 2M x 2N waves
  const int lrow = lane & 15, kg = lane >> 4;

  const int nwg = gridDim.x, cpx = nwg >> 3;     // 960 % 8 == 0
  const int bid = (blockIdx.x & 7)*cpx + (blockIdx.x >> 3);
  const int bx = bid % NBX, by = bid / NBX;
  const int m0 = by*128, n0 = bx*128;

  const unsigned short* Ab = A  + (size_t)m0*KD;
  const unsigned short* Bb = Bt + (size_t)n0*KD;

#define G1STG(tt, p) { \
  _Pragma("unroll") \
  for(int c = 0; c < 4; c++){ \
    const int i_ = tid + c*256; const int r_ = i_ >> 3; \
    const int g_ = (i_ & 7) ^ (r_ & 7); \
    __builtin_amdgcn_global_load_lds((gu32*)(Ab + (size_t)r_*KD + (tt)*64 + g_*8), \
                                     (lu32*)(&S[p][0][i_*8]), 16, 0, 0); \
  } \
  _Pragma("unroll") \
  for(int c = 0; c < 4; c++){ \
    const int i_ = tid + c*256; const int r_ = i_ >> 3; \
    const int g_ = (i_ & 7) ^ (r_ & 7); \
    __builtin_amdgcn_global_load_lds((gu32*)(Bb + (size_t)r_*KD + (tt)*64 + g_*8), \
                                     (lu32*)(&S[p][1][i_*8]), 16, 0, 0); \
  } \
}

  f32x4 acc[4][4] = {};
  const int NT = KD/64;                          // 8
  G1STG(0, 0)
  G1STG(1, 1)

  const int arow = wr*64 + lrow;                 // + m*16
  const int brow = wc*64 + lrow;                 // + n*16
  const int gx0 = (kg       ^ (lrow & 7))*8;
  const int gx1 = ((4 + kg) ^ (lrow & 7))*8;

#pragma unroll 1
  for(int t = 0; t < NT; t++){
    const int p = t & 1;
    if(t < NT-1) VMW(8);                         // tile t's 8 loads retired
    else         VMW(0);
    BARR;
    const short* Abuf = &S[p][0][0];
    const short* Bbuf = &S[p][1][0];
    bf16x8 af[4], bg[4];
#pragma unroll
    for(int n = 0; n < 4; n++) bg[n] = *(const bf16x8*)(Bbuf + (brow + n*16)*64 + gx0);
#pragma unroll
    for(int m = 0; m < 4; m++) af[m] = *(const bf16x8*)(Abuf + (arow + m*16)*64 + gx0);
    __builtin_amdgcn_s_setprio(1);
#pragma unroll
    for(int m = 0; m < 4; m++)
#pragma unroll
      for(int n = 0; n < 4; n++)
        acc[m][n] = __builtin_amdgcn_mfma_f32_16x16x32_bf16(af[m], bg[n], acc[m][n], 0, 0, 0);
    __builtin_amdgcn_s_setprio(0);
#pragma unroll
    for(int n = 0; n < 4; n++) bg[n] = *(const bf16x8*)(Bbuf + (brow + n*16)*64 + gx1);
#pragma unroll
    for(int m = 0; m < 4; m++) af[m] = *(const bf16x8*)(Abuf + (arow + m*16)*64 + gx1);
    __builtin_amdgcn_s_setprio(1);
#pragma unroll
    for(int m = 0; m < 4; m++)
#pragma unroll
      for(int n = 0; n < 4; n++)
        acc[m][n] = __builtin_amdgcn_mfma_f32_16x16x32_bf16(af[m], bg[n], acc[m][n], 0, 0, 0);
    __builtin_amdgcn_s_setprio(0);
    BARR;                                        // all waves consumed buf p
    if(t + 2 < NT){ G1STG(t+2, p) }              // restage just-consumed buffer
  }
#undef G1STG

  const int colb = n0 + wc*64 + lrow;
#pragma unroll
  for(int n = 0; n < 4; n++){
    const float bb = bias[colb + n*16];
    float sv = 0.f, qv = 0.f;
#pragma unroll
    for(int m = 0; m < 4; m++)
#pragma unroll
      for(int r = 0; r < 4; r++){
        const float v = acc[m][n][r] + bb; sv += v; qv += v*v;
      }
    sv += __shfl_xor(sv, 16); sv += __shfl_xor(sv, 32);
    qv += __shfl_xor(qv, 16); qv += __shfl_xor(qv, 32);
    if(lane < 16){
      psum[(size_t)(by*2 + wr)*ND + colb + n*16] = sv;
      psq [(size_t)(by*2 + wr)*ND + colb + n*16] = qv;
    }
#pragma unroll
    for(int m = 0; m < 4; m++){
      const int row = m0 + wr*64 + m*16 + kg*4;
#pragma unroll
      for(int r = 0; r < 4; r++)
        obf[(size_t)(row + r)*ND + colb + n*16] = f2bf(acc[m][n][r] + bb);
    }
  }
}

// ---------------------------------------------------------------------------
// Kernel 5 (fused): blocks [0,4): BN finalize (240 partial rows -> sc/sh).
// Blocks [4, 4+2048): w2[1024,2048] f32 -> w2t[2048,1024] bf16 transpose.
// ---------------------------------------------------------------------------
__global__ __launch_bounds__(256) void k_bnw(const float* __restrict__ psum,
                                             const float* __restrict__ psq,
                                             const float* __restrict__ bn_g,
                                             const float* __restrict__ bn_b,
                                             float* __restrict__ sc,
                                             float* __restrict__ sh,
                                             const float* __restrict__ w2,
                                             unsigned short* __restrict__ w2t){
  if(blockIdx.x < 4){
    const int c = blockIdx.x*256 + threadIdx.x;
    float s = 0.f, q = 0.f;
    for(int i = 0; i < 240; i++){ s += psum[(size_t)i*HH + c]; q += psq[(size_t)i*HH + c]; }
    const float mu  = s * (1.0f/NROWS);
    const float var = q * (1.0f/NROWS) - mu*mu;
    const float sv  = bn_g[c] / sqrtf(var + 1e-5f);
    sc[c] = sv;
    sh[c] = bn_b[c] - mu*sv;
    return;
  }
  __shared__ float tile[32][33];
  const int blk = blockIdx.x - 4;               // 2048 blocks: 64 n-tiles x 32 k-tiles
  const int n0 = (blk & 63)*32, k0 = (blk >> 6)*32;
  const int r = threadIdx.x >> 3, c4 = (threadIdx.x & 7)*4;
  const float4 v = *(const float4*)(w2 + (size_t)(k0 + r)*EE + n0 + c4);
  tile[r][c4+0] = v.x; tile[r][c4+1] = v.y; tile[r][c4+2] = v.z; tile[r][c4+3] = v.w;
  __syncthreads();
  ushort4 u;
  u.x = f2bf(tile[c4+0][r]); u.y = f2bf(tile[c4+1][r]);
  u.z = f2bf(tile[c4+2][r]); u.w = f2bf(tile[c4+3][r]);
  *(ushort4*)(w2t + (size_t)(n0 + r)*HH + k0 + c4) = u;
}

// ---------------------------------------------------------------------------
// Kernel 6: BN+ReLU in place on x1 (bf16) + pkey init.
// ---------------------------------------------------------------------------
__global__ __launch_bounds__(256) void k_bnrelu(unsigned short* __restrict__ x1,
                                                const float* __restrict__ sc,
                                                const float* __restrict__ sh,
                                                unsigned* __restrict__ pkey){
  const size_t i = (size_t)blockIdx.x*256 + threadIdx.x;   // chunk of 8 bf16
  const int c0 = (int)((i*8) & (HH-1));
  uint4 u = ((uint4*)x1)[i];
  unsigned short* us = (unsigned short*)&u;
  const float4 s0 = *(const float4*)(sc + c0), s1 = *(const float4*)(sc + c0 + 4);
  const float4 h0 = *(const float4*)(sh + c0), h1 = *(const float4*)(sh + c0 + 4);
  const float scv[8] = {s0.x,s0.y,s0.z,s0.w,s1.x,s1.y,s1.z,s1.w};
  const float shv[8] = {h0.x,h0.y,h0.z,h0.w,h1.x,h1.y,h1.z,h1.w};
#pragma unroll
  for(int j = 0; j < 8; j++)
    us[j] = f2bf(fmaxf(bf2f(us[j])*scv[j] + shv[j], 0.f));
  ((uint4*)x1)[i] = u;
  if(blockIdx.x < 1024)
    ((uint4*)pkey)[blockIdx.x*256 + threadIdx.x] =
        make_uint4(0x007FFFFFu, 0x007FFFFFu, 0x007FFFFFu, 0x007FFFFFu);  // key(-inf)
}

// ---------------------------------------------------------------------------
// Kernel 7 (GEMM2): 256x256 tile, BK=64, 8 waves, 128KiB dbuf, 8-phase
// counted-vmcnt schedule (R7), segmented max-pool epilogue via LDS atomicMax
// then coalesced global atomicMax (R6).
// ---------------------------------------------------------------------------
__global__ __launch_bounds__(512, 2) void k_g2(const unsigned short* __restrict__ A,
                                               const unsigned short* __restrict__ Bt,
                                               const int* __restrict__ lensk,
                                               unsigned* __restrict__ pkey){
  const int KD = HH, ND = EE, NBX = EE/256;      // 1024, 2048, 8
  __shared__ short S[2][2][256*64];              // 128 KiB
  const int tid  = threadIdx.x;
  const int wave = tid >> 6, lane = tid & 63;
  const int wr = wave >> 2, wc = wave & 3;       // 2M x 4N waves
  const int lrow = lane & 15, kg = lane >> 4;

  const int nwg = gridDim.x, cpx = nwg >> 3;
  const int bid = (blockIdx.x & 7)*cpx + (blockIdx.x >> 3);
  const int bx = bid % NBX, by = bid / NBX;
  const int m0 = by*256, n0 = bx*256;

  const unsigned short* Ab = A  + (size_t)m0*KD;
  const unsigned short* Bb = Bt + (size_t)n0*KD;

#define STG_A(tt, p, c) { \
  const int i_ = tid + (c)*512; const int r_ = i_ >> 3; \
  const int g_ = (i_ & 7) ^ (r_ & 7); \
  __builtin_amdgcn_global_load_lds((gu32*)(Ab + (size_t)r_*KD + (tt)*64 + g_*8), \
                                   (lu32*)(&S[p][0][i_*8]), 16, 0, 0); }
#define STG_B(tt, p, c) { \
  const int i_ = tid + (c)*512; const int r_ = i_ >> 3; \
  const int g_ = (i_ & 7) ^ (r_ & 7); \
  __builtin_amdgcn_global_load_lds((gu32*)(Bb + (size_t)r_*KD + (tt)*64 + g_*8), \
                                   (lu32*)(&S[p][1][i_*8]), 16, 0, 0); }
#define DSR_B(gx)  _Pragma("unroll") for(int n = 0; n < 4; n++) \
    bg[n] = *(const bf16x8*)(Bbuf + (brow + n*16)*64 + (gx));
#define DSR_AL(gx) _Pragma("unroll") for(int m = 0; m < 4; m++) \
    af[m] = *(const bf16x8*)(Abuf + (arow + m*16)*64 + (gx));
#define DSR_AH(gx) _Pragma("unroll") for(int m = 0; m < 4; m++) \
    af[m] = *(const bf16x8*)(Abuf + (arow + 64 + m*16)*64 + (gx));
#define MFMA_L do{ __builtin_amdgcn_s_setprio(1); \
  _Pragma("unroll") for(int m = 0; m < 4; m++) \
  _Pragma("unroll") for(int n = 0; n < 4; n++) \
    acc[m][n] = __builtin_amdgcn_mfma_f32_16x16x32_bf16(af[m], bg[n], acc[m][n], 0, 0, 0); \
  __builtin_amdgcn_s_setprio(0); }while(0)
#define MFMA_H do{ __builtin_amdgcn_s_setprio(1); \
  _Pragma("unroll") for(int m = 0; m < 4; m++) \
  _Pragma("unroll") for(int n = 0; n < 4; n++) \
    acc[4+m][n] = __builtin_amdgcn_mfma_f32_16x16x32_bf16(af[m], bg[n], acc[4+m][n], 0, 0, 0); \
  __builtin_amdgcn_s_setprio(0); }while(0)

  f32x4 acc[8][4] = {};
  const int NT = KD/64;

  const int arow = wr*128 + lrow;
  const int brow = wc*64  + lrow;
  const int gx0 = (kg       ^ (lrow & 7))*8;
  const int gx1 = ((4 + kg) ^ (lrow & 7))*8;

  STG_A(0, 0, 0) STG_A(0, 0, 2)
  STG_B(0, 0, 0) STG_B(0, 0, 1) STG_B(0, 0, 2) STG_B(0, 0, 3)
  STG_A(0, 0, 1) STG_A(0, 0, 3)
  VMW(2); BARR;

#pragma unroll 1
  for(int t = 0; t < NT-1; t++){
    const int p = t & 1, q = p ^ 1;
    const short* Abuf = &S[p][0][0];
    const short* Bbuf = &S[p][1][0];
    bf16x8 bg[4], af[4];
    DSR_B(gx0); DSR_AL(gx0);
    STG_A(t+1, q, 0) STG_A(t+1, q, 2)
    VMW(2);
    BARR; LGK0;
    MFMA_L;
    BARR;
    DSR_AH(gx0);
    STG_B(t+1, q, 0) STG_B(t+1, q, 1)
    BARR; LGK0;
    MFMA_H;
    BARR;
    DSR_B(gx1); DSR_AL(gx1);
    STG_B(t+1, q, 2) STG_B(t+1, q, 3)
    BARR; LGK0;
    MFMA_L;
    BARR;
    DSR_AH(gx1);
    STG_A(t+1, q, 1) STG_A(t+1, q, 3)
    VMW(2);
    BARR; LGK0;
    MFMA_H;
    BARR;
  }
  {
    const int p = (NT-1) & 1;
    const short* Abuf = &S[p][0][0];
    const short* Bbuf = &S[p][1][0];
    bf16x8 bg[4], af[4];
    DSR_B(gx0); DSR_AL(gx0);
    VMW(0);
    BARR; LGK0;
    MFMA_L;
    BARR;
    DSR_AH(gx0);
    BARR; LGK0;
    MFMA_H;
    BARR;
    DSR_B(gx1); DSR_AL(gx1);
    BARR; LGK0;
    MFMA_L;
    BARR;
    DSR_AH(gx1);
    LGK0;
    MFMA_H;
  }
#undef STG_A
#undef STG_B
#undef DSR_B
#undef DSR_AL
#undef DSR_AH
#undef MFMA_L
#undef MFMA_H

  // ---- two-level segmented max-pool: regs -> LDS (atomicMax) -> global ----
  __syncthreads();
  unsigned* pool = (unsigned*)&S[0][0][0];
  const int b0 = m0 / KK;
  const int b1 = (m0 + 255) / KK;
  const int nseg = b1 - b0 + 1;                  // <= 10
  for(int i = tid; i < nseg*256; i += 512) pool[i] = 0x007FFFFFu;   // fkey(-inf)
  __syncthreads();
  const int lcol = wc*64 + lrow;
  {
    int cur_b = -1;
    float mx[4];
#pragma unroll
    for(int m = 0; m < 8; m++){
#pragma unroll
      for(int r = 0; r < 4; r++){
        const int row = m0 + wr*128 + m*16 + kg*4 + r;
        const int bt = row / KK;
        const int rr = row - bt*KK;
        if(bt != cur_b){
          if(cur_b >= 0){
#pragma unroll
            for(int n = 0; n < 4; n++)
              atomicMax(&pool[(cur_b - b0)*256 + lcol + n*16], fkey(mx[n]));
          }
          cur_b = bt;
#pragma unroll
          for(int n = 0; n < 4; n++) mx[n] = -INFINITY;
        }
        if(rr < lensk[bt]){
#pragma unroll
          for(int n = 0; n < 4; n++) mx[n] = fmaxf(mx[n], acc[m][n][r]);
        }
      }
    }
#pragma unroll
    for(int n = 0; n < 4; n++)
      atomicMax(&pool[(cur_b - b0)*256 + lcol + n*16], fkey(mx[n]));
  }
  __syncthreads();
  for(int e = tid; e < nseg*256; e += 512){
    const int seg = e >> 8, col = e & 255;
    atomicMax(&pkey[(size_t)(b0 + seg)*ND + n0 + col], pool[e]);
  }
}

// ---------------------------------------------------------------------------
// Kernel 8: finalize output.
// ---------------------------------------------------------------------------
__global__ __launch_bounds__(256) void k_final(const unsigned* __restrict__ pkey,
                                               const float* __restrict__ b2,
                                               const unsigned short* __restrict__ nbbf,
                                               float* __restrict__ out){
  const size_t i = (size_t)blockIdx.x*256 + threadIdx.x;   // per 4 elems
  const int c0 = (int)((i*4) & (EE-1));
  const uint4 k = ((const uint4*)pkey)[i];
  const ushort4 nb4 = ((const ushort4*)nbbf)[i];
  const float4 b = *(const float4*)(b2 + c0);
  float4 o;
  o.x = fdec(k.x) + b.x + bf2f(nb4.x);
  o.y = fdec(k.y) + b.y + bf2f(nb4.y);
  o.z = fdec(k.z) + b.z + bf2f(nb4.z);
  o.w = fdec(k.w) + b.w + bf2f(nb4.w);
  ((float4*)out)[i] = o;
}

// ---------------------------------------------------------------------------
extern "C" void kernel_launch(void* const* d_in, const int* in_sizes, int n_in,
                              void* d_out, int out_size, void* d_ws, size_t ws_size,
                              hipStream_t stream){
  const float* features = (const float*)d_in[0];
  const float* atten    = (const float*)d_in[1];
  const int*   text     = (const int*)  d_in[2];
  const float* dlp_w    = (const float*)d_in[4];
  const float* dlp_b    = (const float*)d_in[5];
  const float* dlp_lw   = (const float*)d_in[6];
  const float* dlp_lb   = (const float*)d_in[7];
  const float* w1       = (const float*)d_in[8];
  const float* b1       = (const float*)d_in[9];
  const float* bn_g     = (const float*)d_in[10];
  const float* bn_b     = (const float*)d_in[11];
  const float* w2       = (const float*)d_in[12];
  const float* b2       = (const float*)d_in[13];
  float* out = (float*)d_out;

  // Workspace layout with lifetime aliasing:
  char* ws = (char*)d_ws;
  float*          psum   = (float*)(ws + 0);               //   983,040 (240x1024)
  float*          psq    = (float*)(ws + 983040);          //   983,040
  unsigned short* w1t    = (unsigned short*)(ws + 1966080);// 1,048,576
  float*          hval   = (float*)(ws + 3014656);         //   491,520
  unsigned*       pkey   = (unsigned*)(ws + 0);            // 4,194,304 (overlay, live from k_bnrelu on)
  int*            lensk  = (int*)(ws + 4194304);           //     2,048
  float*          sc     = (float*)(ws + 4196352);         //     4,096
  float*          sh     = (float*)(ws + 4200448);         //     4,096
  unsigned short* nfeats = (unsigned short*)(ws + 4204544);// 15,728,640
  unsigned short* w2t    = (unsigned short*)(ws + 4204544);// 4,194,304 (overlays nfeats after k_g1)
  unsigned short* x1     = (unsigned short*)(ws + 19933184);//31,457,280
  unsigned short* nbbf   = (unsigned short*)(ws + 51390464);// 2,097,152

  k_pg<<<BS + 512, 256, 0, stream>>>(atten, text, features, dlp_w, dlp_b,
                                     w1, w1t, nfeats, hval, lensk);
  k_dlp<<<dim3(16, NG), 256, 0, stream>>>(hval, dlp_lw, dlp_lb, nbbf);
  k_l2nb<<<BS, 256, 0, stream>>>(nbbf);
  k_g1<<<(HH/128)*(NROWS/128), 256, 0, stream>>>(nfeats, w1t, b1, x1, psum, psq);
  k_bnw<<<4 + 2048, 256, 0, stream>>>(psum, psq, bn_g, bn_b, sc, sh, w2, w2t);
  k_bnrelu<<<(NROWS*HH/8)/256, 256, 0, stream>>>(x1, sc, sh, pkey);
  k_g2<<<(EE/256)*(NROWS/256), 512, 0, stream>>>(x1, w2t, lensk, pkey);
  k_final<<<(BS*EE/4)/256, 256, 0, stream>>>(pkey, b2, nbbf, out);
}